// Round 3
// baseline (2873.108 us; speedup 1.0000x reference)
//
#include <hip/hip_runtime.h>

#define N_NODES 100000
#define N_EDGES 1600000
#define D 128

// ---------------- threefry2x32 (exact JAX semantics) ----------------
struct KeyPair { unsigned a, b; };

__host__ __device__ constexpr unsigned rotl32c(unsigned x, int d) {
    return (x << d) | (x >> (32 - d));
}

__host__ __device__ constexpr KeyPair threefry2x32(unsigned k0, unsigned k1,
                                                   unsigned x0, unsigned x1) {
    unsigned ks0 = k0, ks1 = k1, ks2 = 0x1BD11BDAu ^ k0 ^ k1;
    const int rot0[4] = {13, 15, 26, 6};
    const int rot1[4] = {17, 29, 16, 24};
    x0 += ks0; x1 += ks1;
    for (int i = 0; i < 4; ++i) { x0 += x1; x1 = rotl32c(x1, rot0[i]); x1 ^= x0; }
    x0 += ks1; x1 += ks2 + 1u;
    for (int i = 0; i < 4; ++i) { x0 += x1; x1 = rotl32c(x1, rot1[i]); x1 ^= x0; }
    x0 += ks2; x1 += ks0 + 2u;
    for (int i = 0; i < 4; ++i) { x0 += x1; x1 = rotl32c(x1, rot0[i]); x1 ^= x0; }
    x0 += ks0; x1 += ks1 + 3u;
    for (int i = 0; i < 4; ++i) { x0 += x1; x1 = rotl32c(x1, rot1[i]); x1 ^= x0; }
    x0 += ks1; x1 += ks2 + 4u;
    for (int i = 0; i < 4; ++i) { x0 += x1; x1 = rotl32c(x1, rot0[i]); x1 ^= x0; }
    x0 += ks2; x1 += ks0 + 5u;
    return {x0, x1};
}

// folded key = threefry(key(42)=(0,42), seed(7)=(0,7)) — compile-time constant
constexpr KeyPair FKEY = threefry2x32(0u, 42u, 0u, 7u);

// dropout for flat element index e of x (row-major [N_NODES, D]).
// JAX >= 0.4.36 default: jax_threefry_partitionable=True ->
//   bits(e) = b1 ^ b2 where (b1,b2) = threefry(key, (hi32(e), lo32(e)));
//   here n = 12.8M < 2^32 so hi word is 0.
__device__ __forceinline__ float dropout_val(float xv, unsigned e) {
    KeyPair o = threefry2x32(FKEY.a, FKEY.b, 0u, e);
    unsigned bits = o.a ^ o.b;
    float u = __uint_as_float((bits >> 9) | 0x3f800000u) - 1.0f;
    return (u < 0.9f) ? xv * (1.0f / 0.9f) : 0.0f;
}

// ---------------- kernel 1: fused dropout + [N,128]@[128,128] ----------------
__global__ __launch_bounds__(256) void gemm_dropout_kernel(
        const float* __restrict__ x, const float* __restrict__ w,
        float* __restrict__ h) {
    __shared__ float xs[16][128];
    const int t = threadIdx.x;
    const int base = blockIdx.x * (16 * 128);

    #pragma unroll
    for (int i = 0; i < 8; ++i) {
        int idx = t + i * 256;
        float xv = x[base + idx];
        xs[idx >> 7][idx & 127] = dropout_val(xv, (unsigned)(base + idx));
    }
    __syncthreads();

    const int col = t & 127;
    const int g = t >> 7;  // 0 or 1: which 8-row group
    float acc[8] = {0.f, 0.f, 0.f, 0.f, 0.f, 0.f, 0.f, 0.f};

    #pragma unroll 4
    for (int k = 0; k < 128; ++k) {
        float wv = w[k * 128 + col];
        #pragma unroll
        for (int i = 0; i < 8; ++i)
            acc[i] += xs[g * 8 + i][k] * wv;
    }

    const int row0 = blockIdx.x * 16 + g * 8;
    #pragma unroll
    for (int i = 0; i < 8; ++i)
        h[(row0 + i) * 128 + col] = acc[i];
}

// ---------------- kernel 2: COO scatter-add (atomics, float4 gather) --------
__global__ __launch_bounds__(256) void scatter_kernel(
        const float* __restrict__ h, const int* __restrict__ esrc,
        const int* __restrict__ edst, const float* __restrict__ evals,
        float* __restrict__ out) {
    int tid = blockIdx.x * 256 + threadIdx.x;   // < N_EDGES*32 = 51.2M
    int e  = tid >> 5;          // edge index
    int d4 = (tid & 31) << 2;   // dim group: 0,4,...,124
    int s  = esrc[e];
    int dd = edst[e];
    float v = evals[e];
    float4 hv = *reinterpret_cast<const float4*>(h + s * 128 + d4);
    float* o = out + dd * 128 + d4;
    atomicAdd(o + 0, v * hv.x);
    atomicAdd(o + 1, v * hv.y);
    atomicAdd(o + 2, v * hv.z);
    atomicAdd(o + 3, v * hv.w);
}

// ---------------- kernel 3: in-place ReLU ----------------
__global__ __launch_bounds__(256) void relu_kernel(float4* __restrict__ out) {
    int i = blockIdx.x * 256 + threadIdx.x;
    float4 v = out[i];
    v.x = fmaxf(v.x, 0.f);
    v.y = fmaxf(v.y, 0.f);
    v.z = fmaxf(v.z, 0.f);
    v.w = fmaxf(v.w, 0.f);
    out[i] = v;
}

extern "C" void kernel_launch(void* const* d_in, const int* in_sizes, int n_in,
                              void* d_out, int out_size, void* d_ws, size_t ws_size,
                              hipStream_t stream) {
    const float* x     = (const float*)d_in[0];
    const float* w     = (const float*)d_in[1];
    const int*   esrc  = (const int*)d_in[2];
    const int*   edst  = (const int*)d_in[3];
    const float* evals = (const float*)d_in[4];
    float* out = (float*)d_out;
    float* h   = (float*)d_ws;   // N_NODES * D floats = 51.2 MB

    // zero the accumulator (harness poisons d_out with 0xAA)
    hipMemsetAsync(d_out, 0, (size_t)N_NODES * D * sizeof(float), stream);

    gemm_dropout_kernel<<<N_NODES / 16, 256, 0, stream>>>(x, w, h);

    scatter_kernel<<<(N_EDGES * 32) / 256, 256, 0, stream>>>(h, esrc, edst, evals, out);

    relu_kernel<<<(N_NODES * D / 4) / 256, 256, 0, stream>>>((float4*)d_out);
}

// Round 5
// 481.865 us; speedup vs baseline: 5.9625x; 5.9625x over previous
//
#include <hip/hip_runtime.h>

#define N_NODES 100000
#define N_EDGES 1600000
#define D 128
#define SCAN_BLK 1024
#define NB_SCAN 98   // ceil(100000/1024)

// ---------------- threefry2x32 (exact JAX semantics) ----------------
struct KeyPair { unsigned a, b; };

__host__ __device__ constexpr unsigned rotl32c(unsigned x, int d) {
    return (x << d) | (x >> (32 - d));
}

__host__ __device__ constexpr KeyPair threefry2x32(unsigned k0, unsigned k1,
                                                   unsigned x0, unsigned x1) {
    unsigned ks0 = k0, ks1 = k1, ks2 = 0x1BD11BDAu ^ k0 ^ k1;
    const int rot0[4] = {13, 15, 26, 6};
    const int rot1[4] = {17, 29, 16, 24};
    x0 += ks0; x1 += ks1;
    for (int i = 0; i < 4; ++i) { x0 += x1; x1 = rotl32c(x1, rot0[i]); x1 ^= x0; }
    x0 += ks1; x1 += ks2 + 1u;
    for (int i = 0; i < 4; ++i) { x0 += x1; x1 = rotl32c(x1, rot1[i]); x1 ^= x0; }
    x0 += ks2; x1 += ks0 + 2u;
    for (int i = 0; i < 4; ++i) { x0 += x1; x1 = rotl32c(x1, rot0[i]); x1 ^= x0; }
    x0 += ks0; x1 += ks1 + 3u;
    for (int i = 0; i < 4; ++i) { x0 += x1; x1 = rotl32c(x1, rot1[i]); x1 ^= x0; }
    x0 += ks1; x1 += ks2 + 4u;
    for (int i = 0; i < 4; ++i) { x0 += x1; x1 = rotl32c(x1, rot0[i]); x1 ^= x0; }
    x0 += ks2; x1 += ks0 + 5u;
    return {x0, x1};
}

constexpr KeyPair FKEY = threefry2x32(0u, 42u, 0u, 7u);

// partitionable threefry bits: b1^b2 of threefry(key, (0, e))
__device__ __forceinline__ float dropout_val(float xv, unsigned e) {
    KeyPair o = threefry2x32(FKEY.a, FKEY.b, 0u, e);
    unsigned bits = o.a ^ o.b;
    float u = __uint_as_float((bits >> 9) | 0x3f800000u) - 1.0f;
    return (u < 0.9f) ? xv * (1.0f / 0.9f) : 0.0f;
}

// ---------------- kernel: fused dropout + [N,128]@[128,128] ----------------
__global__ __launch_bounds__(256) void gemm_dropout_kernel(
        const float* __restrict__ x, const float* __restrict__ w,
        float* __restrict__ h) {
    __shared__ float xs[16][128];
    const int t = threadIdx.x;
    const int base = blockIdx.x * (16 * 128);

    #pragma unroll
    for (int i = 0; i < 8; ++i) {
        int idx = t + i * 256;
        float xv = x[base + idx];
        xs[idx >> 7][idx & 127] = dropout_val(xv, (unsigned)(base + idx));
    }
    __syncthreads();

    const int col = t & 127;
    const int g = t >> 7;
    float acc[8] = {0.f, 0.f, 0.f, 0.f, 0.f, 0.f, 0.f, 0.f};

    #pragma unroll 4
    for (int k = 0; k < 128; ++k) {
        float wv = w[k * 128 + col];
        #pragma unroll
        for (int i = 0; i < 8; ++i)
            acc[i] += xs[g * 8 + i][k] * wv;
    }

    const int row0 = blockIdx.x * 16 + g * 8;
    #pragma unroll
    for (int i = 0; i < 8; ++i)
        h[(row0 + i) * 128 + col] = acc[i];
}

// ---------------- CSR build: histogram -> scan -> counting sort ----------------
__global__ __launch_bounds__(256) void hist_kernel(
        const int* __restrict__ edst, int* __restrict__ counts) {
    int e = blockIdx.x * 256 + threadIdx.x;
    if (e < N_EDGES) atomicAdd(&counts[edst[e]], 1);
}

__global__ __launch_bounds__(SCAN_BLK) void partial_kernel(
        const int* __restrict__ counts, int* __restrict__ partials) {
    __shared__ int sdata[SCAN_BLK];
    int idx = blockIdx.x * SCAN_BLK + threadIdx.x;
    sdata[threadIdx.x] = (idx < N_NODES) ? counts[idx] : 0;
    __syncthreads();
    for (int s = SCAN_BLK / 2; s > 0; s >>= 1) {
        if (threadIdx.x < s) sdata[threadIdx.x] += sdata[threadIdx.x + s];
        __syncthreads();
    }
    if (threadIdx.x == 0) partials[blockIdx.x] = sdata[0];
}

__global__ void scanpartials_kernel(int* __restrict__ partials) {
    if (threadIdx.x == 0) {
        int run = 0;
        for (int b = 0; b < NB_SCAN; ++b) {
            int t = partials[b];
            partials[b] = run;
            run += t;
        }
    }
}

__global__ __launch_bounds__(SCAN_BLK) void finalize_kernel(
        const int* __restrict__ counts, const int* __restrict__ partials,
        int* __restrict__ offsets, int* __restrict__ cursor) {
    __shared__ int sc[SCAN_BLK];
    int idx = blockIdx.x * SCAN_BLK + threadIdx.x;
    int v = (idx < N_NODES) ? counts[idx] : 0;
    sc[threadIdx.x] = v;
    __syncthreads();
    // Hillis-Steele inclusive scan
    for (int off = 1; off < SCAN_BLK; off <<= 1) {
        int t = (threadIdx.x >= off) ? sc[threadIdx.x - off] : 0;
        __syncthreads();
        sc[threadIdx.x] += t;
        __syncthreads();
    }
    if (idx < N_NODES) {
        int base = partials[blockIdx.x];
        int excl = base + sc[threadIdx.x] - v;
        offsets[idx] = excl;
        cursor[idx] = excl;
        if (idx == N_NODES - 1) offsets[N_NODES] = base + sc[threadIdx.x];
    }
}

__global__ __launch_bounds__(256) void sort_kernel(
        const int* __restrict__ esrc, const int* __restrict__ edst,
        const float* __restrict__ evals, int* __restrict__ cursor,
        int* __restrict__ ssrc, float* __restrict__ sval) {
    int e = blockIdx.x * 256 + threadIdx.x;
    if (e < N_EDGES) {
        int d = edst[e];
        int pos = atomicAdd(&cursor[d], 1);
        ssrc[pos] = esrc[e];
        sval[pos] = evals[e];
    }
}

// ---------------- gather + fused ReLU (no atomics) ----------------
__global__ __launch_bounds__(128) void gather_kernel(
        const float* __restrict__ h, const int* __restrict__ offsets,
        const int* __restrict__ ssrc, const float* __restrict__ sval,
        float* __restrict__ out) {
    __shared__ int   s_src[128];
    __shared__ float s_val[128];
    const int node = blockIdx.x;
    const int d = threadIdx.x;
    const int start = offsets[node];
    const int end = offsets[node + 1];

    float acc = 0.f;
    for (int base = start; base < end; base += 128) {
        int n = min(128, end - base);
        if (threadIdx.x < n) {
            s_src[threadIdx.x] = ssrc[base + threadIdx.x];
            s_val[threadIdx.x] = sval[base + threadIdx.x];
        }
        __syncthreads();
        #pragma unroll 4
        for (int j = 0; j < n; ++j)
            acc += s_val[j] * h[s_src[j] * 128 + d];
        __syncthreads();
    }
    out[node * 128 + d] = fmaxf(acc, 0.f);
}

extern "C" void kernel_launch(void* const* d_in, const int* in_sizes, int n_in,
                              void* d_out, int out_size, void* d_ws, size_t ws_size,
                              hipStream_t stream) {
    const float* x     = (const float*)d_in[0];
    const float* w     = (const float*)d_in[1];
    const int*   esrc  = (const int*)d_in[2];
    const int*   edst  = (const int*)d_in[3];
    const float* evals = (const float*)d_in[4];
    float* out = (float*)d_out;

    char* ws = (char*)d_ws;
    float* h        = (float*)(ws);                 // 51,200,000 B
    int*   counts   = (int*)(ws + 51200000);        //    400,000 B
    int*   offsets  = (int*)(ws + 51600000);        //    400,128 B (100001 ints)
    int*   cursor   = (int*)(ws + 52000128);        //    400,000 B
    int*   ssrc     = (int*)(ws + 52400128);        //  6,400,000 B
    float* sval     = (float*)(ws + 58800128);      //  6,400,000 B
    int*   partials = (int*)(ws + 65200128);        //        512 B

    // zero only the histogram (ws is poisoned 0xAA each call)
    hipMemsetAsync(counts, 0, N_NODES * sizeof(int), stream);

    // CSR build
    hist_kernel<<<(N_EDGES + 255) / 256, 256, 0, stream>>>(edst, counts);
    partial_kernel<<<NB_SCAN, SCAN_BLK, 0, stream>>>(counts, partials);
    scanpartials_kernel<<<1, 64, 0, stream>>>(partials);
    finalize_kernel<<<NB_SCAN, SCAN_BLK, 0, stream>>>(counts, partials, offsets, cursor);
    sort_kernel<<<(N_EDGES + 255) / 256, 256, 0, stream>>>(esrc, edst, evals, cursor, ssrc, sval);

    // dense transform
    gemm_dropout_kernel<<<N_NODES / 16, 256, 0, stream>>>(x, w, h);

    // aggregate + ReLU (writes every output element; no d_out memset needed)
    gather_kernel<<<N_NODES, 128, 0, stream>>>(h, offsets, ssrc, sval, out);
}